// Round 13
// baseline (265.777 us; speedup 1.0000x reference)
//
#include <hip/hip_runtime.h>
#include <stdint.h>

// ---------------------------------------------------------------------------
// GCN forward on MI355X:
//   d = rsqrt(A.sum(1));  out = dA d relu(dA d (X W1) + b1) W2 + b2 (fused)
// Big A_bf GEMMs: m201-style 8-phase schedule. 256x256 tile, BK=64, 8 waves
// (2Mx4N), 2 double-buffers (128KB LDS). r12 FIX: vmcnt certification moved
// to END of tile (p3, before barrier) so it precedes the next tile's
// ds_reads — reads-before-wait was the r12 race (absmax 1e-2).
// Per tile t (buf b = t&1):
//  p0 (k0,m0): read af(m0,k0)+bfr(k0); stage A{0,2}(t+1)->b^1
//  p1 (k0,m1): read af(m1,k0);         stage A{1,3}(t+1)->b^1
//  p2 (k1,m0): read af(m0,k1)+bfr(k1)
//  p3 (k1,m1): read af(m1,k1);         stage B(t+2)->b; vmcnt(4|0)
// Each phase ends: barrier; lgkmcnt(0); sched_barrier; setprio(1); 16 MFMA;
// setprio(0); barrier.  Ledger: at t p3 after stgB, outstanding =
// A(t+1)[4]+B(t+2)[4]; vmcnt(4) retires A(t+1)+B(t+1) -> tile t+1 certified
// before t+1 p0 reads (published by end-of-p3 barrier). Prologue: 16 loads,
// vmcnt(8)+barrier certifies tile 0. Tail: t+2>=nt -> vmcnt(0).
// ---------------------------------------------------------------------------

typedef __attribute__((ext_vector_type(8))) __bf16 bf16x8;
typedef __attribute__((ext_vector_type(4))) float f32x4;
typedef __attribute__((ext_vector_type(8))) unsigned short u16x8;

__device__ __forceinline__ unsigned short f2bf(float f) {
  union { float f; uint32_t u; } v; v.f = f;
  uint32_t u = v.u;
  return (unsigned short)((u + 0x7fffu + ((u >> 16) & 1u)) >> 16);  // RNE
}

__device__ __forceinline__ float bf2f(unsigned short u) {
  union { uint32_t u; float f; } v; v.u = ((uint32_t)u) << 16; return v.f;
}

__device__ __forceinline__ void async_cp16(const void* g, void* lds) {
  auto gp = (const __attribute__((address_space(1))) uint32_t*)g;
  auto lp = (__attribute__((address_space(3))) uint32_t*)lds;
  __builtin_amdgcn_global_load_lds(gp, lp, 16, 0, 0);
}

// --- kernel 1: per-row sum of fp32 A + fp32->bf16 conversion ----------------
__global__ __launch_bounds__(256) void k_rowsum_convert(
    const float* __restrict__ A, unsigned short* __restrict__ Abf,
    float* __restrict__ dvec, int ncols) {
  const int row = blockIdx.x;
  const float* arow = A + (size_t)row * ncols;
  unsigned short* orow = Abf + (size_t)row * ncols;
  float s = 0.f;
  for (int c = threadIdx.x * 4; c < ncols; c += 256 * 4) {
    float4 v = *(const float4*)(arow + c);
    s += (v.x + v.y) + (v.z + v.w);
    ushort4 o;
    o.x = f2bf(v.x); o.y = f2bf(v.y); o.z = f2bf(v.z); o.w = f2bf(v.w);
    *(ushort4*)(orow + c) = o;
  }
  #pragma unroll
  for (int off = 32; off > 0; off >>= 1) s += __shfl_down(s, off);
  __shared__ float red[4];
  if ((threadIdx.x & 63) == 0) red[threadIdx.x >> 6] = s;
  __syncthreads();
  if (threadIdx.x == 0) {
    float t = (red[0] + red[1]) + (red[2] + red[3]);
    dvec[row] = 1.0f / sqrtf(t);
  }
}

// --- kernel 2: elementwise fp32 -> bf16 -------------------------------------
__global__ __launch_bounds__(256) void k_f32_to_bf16(
    const float* __restrict__ in, unsigned short* __restrict__ out, int n4) {
  int i = blockIdx.x * 256 + threadIdx.x;
  if (i < n4) {
    float4 v = ((const float4*)in)[i];
    ushort4 o;
    o.x = f2bf(v.x); o.y = f2bf(v.y); o.z = f2bf(v.z); o.w = f2bf(v.w);
    ((ushort4*)out)[i] = o;
  }
}

// --- kernel 3: transpose + convert 512x512 weight: out[n][k] = in[k][n] -----
__global__ __launch_bounds__(256) void k_transpose_bf16(
    const float* __restrict__ in, unsigned short* __restrict__ out, int dim) {
  int o = blockIdx.x * 256 + threadIdx.x;
  if (o < dim * dim) {
    int k = o % dim;
    int n = o / dim;
    out[o] = f2bf(in[k * dim + n]);
  }
}

// --- small GEMM (proven): C[M,N] = bf16(dvec[col] * Aop[M,K] * Bt[N,K]^T) ---
template <int MODE>
__global__ __launch_bounds__(256, 2) void gemm_bt(
    const unsigned short* __restrict__ Aop,
    const unsigned short* __restrict__ Bt,
    void* __restrict__ Cout,
    const float* __restrict__ dvec,
    const float* __restrict__ bias,
    int M, int N, int K) {
  constexpr int BM = 128, BN = 64, BK = 32;
  __shared__ unsigned short As[BM * BK];
  __shared__ unsigned short Bs[BN * BK];

  const int tid = threadIdx.x;
  const int w = tid >> 6;
  const int l = tid & 63;
  const int rowBase = blockIdx.y * BM;
  const int colBase = blockIdx.x * BN;
  const int waveM = w >> 1;
  const int waveN = w & 1;

  f32x4 acc[4][2];
  const f32x4 fz = {0.f, 0.f, 0.f, 0.f};
  #pragma unroll
  for (int m = 0; m < 4; ++m)
    #pragma unroll
    for (int n = 0; n < 2; ++n) acc[m][n] = fz;

  const int chunkRow = l >> 2;
  const int kOff = (l & 3) * 8;
  const unsigned short* gA0 = Aop + (size_t)(rowBase + w * 16 + chunkRow) * K + kOff;
  const unsigned short* gA1 = gA0 + (size_t)64 * K;
  const unsigned short* gB0 = Bt + (size_t)(colBase + w * 16 + chunkRow) * K + kOff;
  unsigned short* lA0 = As + w * 512;
  unsigned short* lA1 = As + (w + 4) * 512;
  unsigned short* lB0 = Bs + w * 512;

  const int kfrag = (l >> 4) * 8;
  const int lrow = l & 15;

  for (int k0 = 0; k0 < K; k0 += BK) {
    async_cp16(gA0 + k0, lA0);
    async_cp16(gA1 + k0, lA1);
    async_cp16(gB0 + k0, lB0);
    __syncthreads();

    bf16x8 af[4], bfr[2];
    #pragma unroll
    for (int m = 0; m < 4; ++m)
      af[m] = *(const bf16x8*)(As + (waveM * 64 + m * 16 + lrow) * BK + kfrag);
    #pragma unroll
    for (int n = 0; n < 2; ++n)
      bfr[n] = *(const bf16x8*)(Bs + (waveN * 32 + n * 16 + lrow) * BK + kfrag);

    #pragma unroll
    for (int m = 0; m < 4; ++m)
      #pragma unroll
      for (int n = 0; n < 2; ++n)
        acc[m][n] = __builtin_amdgcn_mfma_f32_16x16x32_bf16(af[m], bfr[n],
                                                            acc[m][n], 0, 0, 0);
    __syncthreads();
  }

  const int erow0 = rowBase + waveM * 64 + (l >> 4) * 4;
  const int ecol0 = colBase + waveN * 32 + (l & 15);
  #pragma unroll
  for (int m = 0; m < 4; ++m) {
    #pragma unroll
    for (int n = 0; n < 2; ++n) {
      #pragma unroll
      for (int j = 0; j < 4; ++j) {
        const int rowg = erow0 + m * 16 + j;
        const int colg = ecol0 + n * 16;
        float v = acc[m][n][j];
        if (MODE == 0) {
          v *= dvec[colg];
          ((unsigned short*)Cout)[(size_t)rowg * N + colg] = f2bf(v);
        }
      }
    }
  }
}

// --- big GEMM: see header comment -------------------------------------------
__global__ __launch_bounds__(512, 2) void gemm_big8p(
    const unsigned short* __restrict__ Aop,
    const unsigned short* __restrict__ Bt,
    unsigned short* __restrict__ Pout,
    int M, int N, int K, int kLen) {
  __shared__ char lds[131072];  // 2 bufs x (A 32KB | B 32KB)

  const int tid = threadIdx.x;
  const int w = tid >> 6;       // 0..7
  const int l = tid & 63;

  const int id = blockIdx.x;
  const int q = id & 7, s = id >> 3;
  const int bx = s & 1;
  const int by = ((q & 1) << 4) | (s >> 1);
  const int bz = q >> 1;

  const int rowBase = by * 256;
  const int colBase = bx * 256;
  const int kBase = bz * kLen;
  const int waveM = w >> 2;     // 0..1 -> 128-row slab
  const int waveN = w & 3;      // 0..3 -> 64-col slab

  f32x4 acc[8][4];
  const f32x4 fz = {0.f, 0.f, 0.f, 0.f};
  #pragma unroll
  for (int m = 0; m < 8; ++m)
    #pragma unroll
    for (int n = 0; n < 4; ++n) acc[m][n] = fz;

  // staging: inst i covers rows i*64..i*64+63; lane -> row w*8+(l>>3),
  // slot l&7; pre-swizzled source slot = (l&7) ^ ((l>>3)&7).
  const int srcSwz = ((l & 7) ^ ((l >> 3) & 7)) * 8;
  const unsigned short* aSrc =
      Aop + (size_t)(rowBase + w * 8 + (l >> 3)) * K + kBase + srcSwz;
  const unsigned short* bSrc =
      Bt + (size_t)(colBase + w * 8 + (l >> 3)) * K + kBase + srcSwz;
  const int dstTh = w * 1024 + l * 16;

#define STG_A(i, tt, bb) \
  async_cp16(aSrc + (size_t)(i) * 64 * K + (size_t)(tt) * 64, \
             lds + (bb) + (i) * 8192 + dstTh)
#define STG_B(i, tt, bb) \
  async_cp16(bSrc + (size_t)(i) * 64 * K + (size_t)(tt) * 64, \
             lds + (bb) + 32768 + (i) * 8192 + dstTh)

  const int nt = kLen / 64;  // 32
  // prologue: tiles 0,1 fully (order: Am{0,2}, Am{1,3}, B, per tile)
  STG_A(0, 0, 0); STG_A(2, 0, 0); STG_A(1, 0, 0); STG_A(3, 0, 0);
  STG_B(0, 0, 0); STG_B(1, 0, 0); STG_B(2, 0, 0); STG_B(3, 0, 0);
  STG_A(0, 1, 65536); STG_A(2, 1, 65536); STG_A(1, 1, 65536); STG_A(3, 1, 65536);
  STG_B(0, 1, 65536); STG_B(1, 1, 65536); STG_B(2, 1, 65536); STG_B(3, 1, 65536);
  // certify tile 0 (retire oldest 8 = A(0)+B(0)) BEFORE any reads
  asm volatile("s_waitcnt vmcnt(8)" ::: "memory");
  __builtin_amdgcn_s_barrier();

  const int lrow = l & 15;
  const int kq = l >> 4;         // 16B k-slot within k-half
  const int swz7 = l & 7;        // row&7 of this lane's fragment rows
  const int aRow0 = (waveM * 128 + lrow) * 128;
  const int bRow0 = 32768 + (waveN * 64 + lrow) * 128;
  const int slot0 = ((kq ^ swz7) << 4);            // k-half 0
  const int slot1 = (((4 + kq) ^ swz7) << 4);      // k-half 1

  for (int t = 0; t < nt; ++t) {
    const int base = (t & 1) << 16;
    const int obase = base ^ 65536;
    const char* Ab = lds + base;
    const char* Bb = lds + base;
    const bool stgA = (t + 1 < nt);
    const bool stgB = (t + 2 < nt);

    // ---------------- phase 0: (k0, m0) ----------------
    // reads tile t (certified by t-1 p3 vmcnt + barrier; t=0 by prologue)
    bf16x8 af0[4], bf0[4];
    #pragma unroll
    for (int i = 0; i < 4; ++i)
      af0[i] = *(const bf16x8*)(Ab + aRow0 + i * 16 * 128 + slot0);
    #pragma unroll
    for (int n = 0; n < 4; ++n)
      bf0[n] = *(const bf16x8*)(Bb + bRow0 + n * 16 * 128 + slot0);
    if (stgA && t >= 1) { STG_A(0, t + 1, obase); STG_A(2, t + 1, obase); }
    __builtin_amdgcn_sched_barrier(0);
    __builtin_amdgcn_s_barrier();
    asm volatile("s_waitcnt lgkmcnt(0)" ::: "memory");
    __builtin_amdgcn_sched_barrier(0);
    __builtin_amdgcn_s_setprio(1);
    #pragma unroll
    for (int i = 0; i < 4; ++i)
      #pragma unroll
      for (int n = 0; n < 4; ++n)
        acc[i][n] = __builtin_amdgcn_mfma_f32_16x16x32_bf16(
            af0[i], bf0[n], acc[i][n], 0, 0, 0);
    __builtin_amdgcn_s_setprio(0);
    __builtin_amdgcn_s_barrier();

    // ---------------- phase 1: (k0, m1) ----------------
    bf16x8 af1[4];
    #pragma unroll
    for (int i = 0; i < 4; ++i)
      af1[i] = *(const bf16x8*)(Ab + aRow0 + (64 + i * 16) * 128 + slot0);
    if (stgA && t >= 1) { STG_A(1, t + 1, obase); STG_A(3, t + 1, obase); }
    __builtin_amdgcn_sched_barrier(0);
    __builtin_amdgcn_s_barrier();
    asm volatile("s_waitcnt lgkmcnt(0)" ::: "memory");
    __builtin_amdgcn_sched_barrier(0);
    __builtin_amdgcn_s_setprio(1);
    #pragma unroll
    for (int i = 0; i < 4; ++i)
      #pragma unroll
      for (int n = 0; n < 4; ++n)
        acc[4 + i][n] = __builtin_amdgcn_mfma_f32_16x16x32_bf16(
            af1[i], bf0[n], acc[4 + i][n], 0, 0, 0);
    __builtin_amdgcn_s_setprio(0);
    __builtin_amdgcn_s_barrier();

    // ---------------- phase 2: (k1, m0) ----------------
    bf16x8 af2_[4], bf1[4];
    #pragma unroll
    for (int i = 0; i < 4; ++i)
      af2_[i] = *(const bf16x8*)(Ab + aRow0 + i * 16 * 128 + slot1);
    #pragma unroll
    for (int n = 0; n < 4; ++n)
      bf1[n] = *(const bf16x8*)(Bb + bRow0 + n * 16 * 128 + slot1);
    __builtin_amdgcn_sched_barrier(0);
    __builtin_amdgcn_s_barrier();
    asm volatile("s_waitcnt lgkmcnt(0)" ::: "memory");
    __builtin_amdgcn_sched_barrier(0);
    __builtin_amdgcn_s_setprio(1);
    #pragma unroll
    for (int i = 0; i < 4; ++i)
      #pragma unroll
      for (int n = 0; n < 4; ++n)
        acc[i][n] = __builtin_amdgcn_mfma_f32_16x16x32_bf16(
            af2_[i], bf1[n], acc[i][n], 0, 0, 0);
    __builtin_amdgcn_s_setprio(0);
    __builtin_amdgcn_s_barrier();

    // ---------------- phase 3: (k1, m1) ----------------
    // stage B(t+2) into base-B (B(t) fully consumed at end of p2), then
    // CERTIFY tile t+1: outstanding after stgB = A(t+1)[4] + B(t+2)[4];
    // vmcnt(4) retires A(t+1) + B(t+1). Tail (no stgB): vmcnt(0).
    bf16x8 af3[4];
    #pragma unroll
    for (int i = 0; i < 4; ++i)
      af3[i] = *(const bf16x8*)(Ab + aRow0 + (64 + i * 16) * 128 + slot1);
    if (stgB) { STG_B(0, t + 2, base); STG_B(1, t + 2, base);
                STG_B(2, t + 2, base); STG_B(3, t + 2, base); }
    __builtin_amdgcn_sched_barrier(0);
    if (stgB) { asm volatile("s_waitcnt vmcnt(4)" ::: "memory"); }
    else      { asm volatile("s_waitcnt vmcnt(0)" ::: "memory"); }
    __builtin_amdgcn_s_barrier();
    asm volatile("s_waitcnt lgkmcnt(0)" ::: "memory");
    __builtin_amdgcn_sched_barrier(0);
    __builtin_amdgcn_s_setprio(1);
    #pragma unroll
    for (int i = 0; i < 4; ++i)
      #pragma unroll
      for (int n = 0; n < 4; ++n)
        acc[4 + i][n] = __builtin_amdgcn_mfma_f32_16x16x32_bf16(
            af3[i], bf1[n], acc[4 + i][n], 0, 0, 0);
    __builtin_amdgcn_s_setprio(0);
    __builtin_amdgcn_s_barrier();
  }
#undef STG_A
#undef STG_B

  // epilogue: bf16 partial write. C/D layout: col = lane&15, row = (l>>4)*4+j
  unsigned short* pz = Pout + (size_t)bz * M * N;
  const int erow0 = rowBase + waveM * 128 + (l >> 4) * 4;
  const int ecol0 = colBase + waveN * 64 + (l & 15);
  #pragma unroll
  for (int m = 0; m < 8; ++m) {
    #pragma unroll
    for (int n = 0; n < 4; ++n) {
      #pragma unroll
      for (int j = 0; j < 4; ++j) {
        pz[(size_t)(erow0 + m * 16 + j) * N + ecol0 + n * 16] =
            f2bf(acc[m][n][j]);
      }
    }
  }
}

// --- reduce over 4 bf16 partials + epilogue ---------------------------------
// MODE 1: out bf16 = relu(d_row * sum + bias[col])
// MODE 2: out fp32 = d_row * sum + bias[col]
template <int MODE>
__global__ __launch_bounds__(256) void k_reduce(
    const unsigned short* __restrict__ parts,
    const float* __restrict__ dvec,
    const float* __restrict__ bias,
    void* __restrict__ outp, int M, int N) {
  const size_t MN = (size_t)M * N;
  const size_t idx = ((size_t)blockIdx.x * 256 + threadIdx.x) * 8;
  if (idx >= MN) return;
  const int row = (int)(idx / N);
  const int col = (int)(idx % N);
  const float di = dvec[row];
  float s[8] = {0, 0, 0, 0, 0, 0, 0, 0};
  #pragma unroll
  for (int z = 0; z < 4; ++z) {
    u16x8 v = *(const u16x8*)(parts + z * MN + idx);
    #pragma unroll
    for (int e = 0; e < 8; ++e) s[e] += bf2f(v[e]);
  }
  if (MODE == 1) {
    ushort4 o0, o1;
    unsigned short tmp[8];
    #pragma unroll
    for (int e = 0; e < 8; ++e) {
      float v = di * s[e] + bias[col + e];
      v = v > 0.f ? v : 0.f;
      tmp[e] = f2bf(v);
    }
    o0.x = tmp[0]; o0.y = tmp[1]; o0.z = tmp[2]; o0.w = tmp[3];
    o1.x = tmp[4]; o1.y = tmp[5]; o1.z = tmp[6]; o1.w = tmp[7];
    *(ushort4*)((unsigned short*)outp + idx) = o0;
    *(ushort4*)((unsigned short*)outp + idx + 4) = o1;
  } else {
    float4 o0, o1;
    o0.x = di * s[0] + bias[col + 0];
    o0.y = di * s[1] + bias[col + 1];
    o0.z = di * s[2] + bias[col + 2];
    o0.w = di * s[3] + bias[col + 3];
    o1.x = di * s[4] + bias[col + 4];
    o1.y = di * s[5] + bias[col + 5];
    o1.z = di * s[6] + bias[col + 6];
    o1.w = di * s[7] + bias[col + 7];
    *(float4*)((float*)outp + idx) = o0;
    *(float4*)((float*)outp + idx + 4) = o1;
  }
}

extern "C" void kernel_launch(void* const* d_in, const int* in_sizes, int n_in,
                              void* d_out, int out_size, void* d_ws, size_t ws_size,
                              hipStream_t stream) {
  const float* X  = (const float*)d_in[0];   // [8192, 512]
  const float* A  = (const float*)d_in[1];   // [8192, 8192]
  const float* W1 = (const float*)d_in[2];   // [512, 512]
  const float* b1 = (const float*)d_in[3];   // [512]
  const float* W2 = (const float*)d_in[4];   // [512, 512]
  const float* b2 = (const float*)d_in[5];   // [512]
  float* out = (float*)d_out;                // [8192, 512] fp32

  constexpr int NN = 8192, IN = 512, HID = 512;
  constexpr int KSPLIT = 4;

  // workspace (~177 MiB): d | A_bf | W1t | W2t | P0 | P1 | parts
  char* ws = (char*)d_ws;
  float* ddeg = (float*)ws;                                        // 32KB
  unsigned short* Abf = (unsigned short*)(ws + (32 << 10));        // 128MiB
  unsigned short* W1t = Abf + (size_t)NN * NN;                     // 512KiB
  unsigned short* W2t = W1t + IN * HID;                            // 512KiB
  unsigned short* P0  = W2t + HID * HID;                           // 8MiB
  unsigned short* P1  = P0 + (size_t)NN * HID;                     // 8MiB
  unsigned short* parts = P1 + (size_t)NN * HID;                   // 32MiB

  // 1) degrees + A -> bf16
  k_rowsum_convert<<<NN, 256, 0, stream>>>(A, Abf, ddeg, NN);
  // 2) X -> bf16 (into P0)
  k_f32_to_bf16<<<(NN * IN / 4 + 255) / 256, 256, 0, stream>>>(X, P0, NN * IN / 4);
  // 3) weights transposed+bf16
  k_transpose_bf16<<<(IN * HID + 255) / 256, 256, 0, stream>>>(W1, W1t, IN);
  k_transpose_bf16<<<(HID * HID + 255) / 256, 256, 0, stream>>>(W2, W2t, HID);

  // 4) T1t[h][j] = bf16(d_j * (X@W1)[j][h]) : [512 x 8192]
  gemm_bt<0><<<dim3(NN / 64, HID / 128), 256, 0, stream>>>(
      W1t, P0, P1, ddeg, nullptr, HID, NN, IN);
  // 5) parts[z] = Abf * T1t^T (split-K), then out1 = relu(d*sum + b1) -> P0
  gemm_big8p<<<2 * (NN / 256) * KSPLIT, 512, 0, stream>>>(
      Abf, P1, parts, NN, HID, NN, NN / KSPLIT);
  k_reduce<1><<<(int)((size_t)NN * HID / 8 / 256), 256, 0, stream>>>(
      parts, ddeg, b1, P0, NN, HID);
  // 6) T2t[h][j] = bf16(d_j * (out1@W2)[j][h]) : [512 x 8192]
  gemm_bt<0><<<dim3(NN / 64, HID / 128), 256, 0, stream>>>(
      W2t, P0, P1, ddeg, nullptr, HID, NN, HID);
  // 7) parts[z] = Abf * T2t^T, then out = d*sum + b2 (fp32) -> d_out
  gemm_big8p<<<2 * (NN / 256) * KSPLIT, 512, 0, stream>>>(
      Abf, P1, parts, NN, HID, NN, NN / KSPLIT);
  k_reduce<2><<<(int)((size_t)NN * HID / 8 / 256), 256, 0, stream>>>(
      parts, ddeg, b2, out, NN, HID);
}